// Round 2
// baseline (265.045 us; speedup 1.0000x reference)
//
#include <hip/hip_runtime.h>

// ---------------------------------------------------------------------------
// Compile-time real-spherical-harmonic Clebsch-Gordan tables.
// Replicates the reference's _cg_complex / _u / _cg_real in C++17 constexpr,
// so all CG values fold to literal constants in the kernel and analytic
// zeros are eliminated at compile time.
// ---------------------------------------------------------------------------
namespace cgx {

struct Cplx { double re, im; };

constexpr Cplx cmul(Cplx a, Cplx b) {
  return Cplx{a.re * b.re - a.im * b.im, a.re * b.im + a.im * b.re};
}

constexpr double cfact(int n) {
  double r = 1.0;
  for (int i = 2; i <= n; i++) r *= (double)i;
  return r;
}

constexpr double cabs_(double x) { return x < 0.0 ? -x : x; }

constexpr double csqrt_(double x) {
  if (x <= 0.0) return 0.0;
  double g = x > 1.0 ? x : 1.0;
  for (int it = 0; it < 80; ++it) g = 0.5 * (g + x / g);
  return g;
}

// Complex-basis CG <l3 m3 | l1 m1 l2 m2>, Condon-Shortley.
struct CGC { double v[5][5][9]; };

constexpr CGC cg_complex(int l1, int l2, int l3) {
  CGC C{};
  for (int m1 = -l1; m1 <= l1; m1++) {
    for (int m2 = -l2; m2 <= l2; m2++) {
      int m3 = m1 + m2;
      if (m3 < -l3 || m3 > l3) continue;
      double pre = csqrt_((double)(2 * l3 + 1) * cfact(l1 + l2 - l3) *
                          cfact(l1 - l2 + l3) * cfact(-l1 + l2 + l3) /
                          cfact(l1 + l2 + l3 + 1));
      pre *= csqrt_(cfact(l3 + m3) * cfact(l3 - m3) * cfact(l1 - m1) *
                    cfact(l1 + m1) * cfact(l2 - m2) * cfact(l2 + m2));
      double s = 0.0;
      for (int k = 0; k <= l1 + l2 - l3; k++) {
        int d1 = l1 + l2 - l3 - k, d2 = l1 - m1 - k, d3 = l2 + m2 - k;
        int d4 = l3 - l2 + m1 + k, d5 = l3 - l1 - m2 + k;
        if (d1 < 0 || d2 < 0 || d3 < 0 || d4 < 0 || d5 < 0) continue;
        double d = cfact(k) * cfact(d1) * cfact(d2) * cfact(d3) * cfact(d4) * cfact(d5);
        s += ((k & 1) ? -1.0 : 1.0) / d;
      }
      C.v[m1 + l1][m2 + l2][m3 + l3] = pre * s;
    }
  }
  return C;
}

// Complex -> real SH change of basis, rows = real m index.
struct UMat { Cplx v[9][9]; };

constexpr UMat umat(int l) {
  UMat U{};
  double is2 = csqrt_(0.5);
  U.v[l][l] = Cplx{1.0, 0.0};
  for (int m = 1; m <= l; m++) {
    double sgn = (m & 1) ? -1.0 : 1.0;
    U.v[l + m][l + m] = Cplx{sgn * is2, 0.0};
    U.v[l + m][l - m] = Cplx{is2, 0.0};
    U.v[l - m][l - m] = Cplx{0.0, is2};
    U.v[l - m][l + m] = Cplx{0.0, -sgn * is2};
  }
  return U;
}

struct CGR { float v[5][5][9]; };

constexpr CGR cg_real(int l1, int l2, int l3) {
  CGC C = cg_complex(l1, l2, l3);
  UMat U1 = umat(l1), U2 = umat(l2), U3 = umat(l3);
  double re[5][5][9]{}, im[5][5][9]{};
  double maxre = 0.0, maxim = 0.0;
  for (int a = 0; a < 2 * l1 + 1; a++)
    for (int b = 0; b < 2 * l2 + 1; b++)
      for (int c = 0; c < 2 * l3 + 1; c++) {
        double ar = 0.0, ai = 0.0;
        for (int i = 0; i < 2 * l1 + 1; i++) {
          Cplx u1 = U1.v[a][i];
          if (u1.re == 0.0 && u1.im == 0.0) continue;
          for (int j = 0; j < 2 * l2 + 1; j++) {
            Cplx u2 = U2.v[b][j];
            if (u2.re == 0.0 && u2.im == 0.0) continue;
            int k0 = (i - l1) + (j - l2) + l3;
            if (k0 < 0 || k0 > 2 * l3) continue;
            double cv = C.v[i][j][k0];
            if (cv == 0.0) continue;
            Cplx u3 = U3.v[c][k0];
            if (u3.re == 0.0 && u3.im == 0.0) continue;
            Cplx u12 = cmul(u1, u2);
            Cplx t = cmul(u12, Cplx{u3.re, -u3.im});
            ar += t.re * cv;
            ai += t.im * cv;
          }
        }
        re[a][b][c] = ar;
        im[a][b][c] = ai;
        if (cabs_(ar) > maxre) maxre = cabs_(ar);
        if (cabs_(ai) > maxim) maxim = cabs_(ai);
      }
  CGR R{};
  bool useim = maxim > maxre;
  for (int a = 0; a < 2 * l1 + 1; a++)
    for (int b = 0; b < 2 * l2 + 1; b++)
      for (int c = 0; c < 2 * l3 + 1; c++)
        R.v[a][b][c] = (float)(useim ? im[a][b][c] : re[a][b][c]);
  return R;
}

}  // namespace cgx

// 4 channels per thread, processed as a clang ext-vector (one VGPR quad,
// dwordx4 loads/stores).
typedef float v4 __attribute__((ext_vector_type(4)));

__device__ __forceinline__ v4 v4zero() {
  v4 z = {0.0f, 0.0f, 0.0f, 0.0f};
  return z;
}

// Per-coupling contraction over 4 channels:
//   out[k] += halfmix * sum_ij cg[i][j][k] * xa[i] * xb[j]
// CG values fold to literals; analytic zeros are eliminated at compile time.
template <int L1, int L2, int LO>
__device__ __forceinline__ void do_coupling(const v4* xa, const v4* xb,
                                            v4 halfmix, v4* out) {
  constexpr cgx::CGR t = cgx::cg_real(L1, L2, LO);
#pragma unroll
  for (int k = 0; k < 2 * LO + 1; k++) {
    v4 tp = v4zero();
#pragma unroll
    for (int i = 0; i < 2 * L1 + 1; i++) {
#pragma unroll
      for (int j = 0; j < 2 * L2 + 1; j++) {
        const float cv = t.v[i][j][k];
        if (cv > 1e-7f || cv < -1e-7f)  // constant condition -> folds
          tp = tp + (cv * xa[i]) * xb[j];
      }
    }
    out[k] = out[k] + halfmix * tp;
  }
}

// Layout (floats, per reference):
//  in row (1152):  x0 @ 0 (1x128), x1 @ 128 (3x128), x2 @ 512 (5x128)
//  out row (3200): o0 @ 0, o1 @ 128 (3x128), o2 @ 512 (5x128),
//                  o3 @ 1152 (7x128), o4 @ 2048 (9x128)
//  keep: l0 @ 0, l1 @ 128, l2 @ 256;  mix: 19 couplings x 128, lo-major.

__global__ __launch_bounds__(256) void selfmix_kernel(
    const float* __restrict__ x, const float* __restrict__ keep,
    const float* __restrict__ mix, float* __restrict__ out, int B) {
  int tid = blockIdx.x * 256 + threadIdx.x;
  int b = tid >> 5;        // 32 threads cover the 128 channels
  int c0 = (tid & 31) * 4; // base channel of this thread's float4
  if (b >= B) return;

  const v4* xr = reinterpret_cast<const v4*>(x + (size_t)b * 1152 + c0);
  v4* ob = reinterpret_cast<v4*>(out + (size_t)b * 3200 + c0);
  const v4* kp = reinterpret_cast<const v4*>(keep + c0);
  const v4* mp = reinterpret_cast<const v4*>(mix + c0);
  const float half = 0.5f;

  // x is touched exactly once per thread -> non-temporal loads.
  v4 x2[5];
#pragma unroll
  for (int m = 0; m < 5; m++) x2[m] = __builtin_nontemporal_load(xr + 128 + m * 32);
  v4 x1[3];
#pragma unroll
  for (int m = 0; m < 3; m++) x1[m] = __builtin_nontemporal_load(xr + 32 + m * 32);
  v4 x0[1];
  x0[0] = __builtin_nontemporal_load(xr);

  // ---- lout = 4 (depends only on x2); store immediately to free regs ----
  {
    v4 o4[9];
#pragma unroll
    for (int m = 0; m < 9; m++) o4[m] = v4zero();
    do_coupling<2, 2, 4>(x2, x2, half * mp[18 * 32], o4);
#pragma unroll
    for (int m = 0; m < 9; m++)
      __builtin_nontemporal_store(o4[m], ob + 512 + m * 32);
  }

  // ---- lout = 3 ----
  {
    v4 o3[7];
#pragma unroll
    for (int m = 0; m < 7; m++) o3[m] = v4zero();
    do_coupling<1, 2, 3>(x1, x2, half * mp[15 * 32], o3);
    do_coupling<2, 1, 3>(x2, x1, half * mp[16 * 32], o3);
    do_coupling<2, 2, 3>(x2, x2, half * mp[17 * 32], o3);
#pragma unroll
    for (int m = 0; m < 7; m++)
      __builtin_nontemporal_store(o3[m], ob + 288 + m * 32);
  }

  // ---- lout = 2 (keep path seeds the accumulator) ----
  {
    v4 o2[5];
    v4 k2 = kp[2 * 32];
#pragma unroll
    for (int m = 0; m < 5; m++) o2[m] = k2 * x2[m];
    do_coupling<0, 2, 2>(x0, x2, half * mp[9 * 32], o2);
    do_coupling<1, 1, 2>(x1, x1, half * mp[10 * 32], o2);
    do_coupling<1, 2, 2>(x1, x2, half * mp[11 * 32], o2);
    do_coupling<2, 0, 2>(x2, x0, half * mp[12 * 32], o2);
    do_coupling<2, 1, 2>(x2, x1, half * mp[13 * 32], o2);
    do_coupling<2, 2, 2>(x2, x2, half * mp[14 * 32], o2);
#pragma unroll
    for (int m = 0; m < 5; m++)
      __builtin_nontemporal_store(o2[m], ob + 128 + m * 32);
  }

  // ---- lout = 1 ----
  {
    v4 o1[3];
    v4 k1 = kp[1 * 32];
#pragma unroll
    for (int m = 0; m < 3; m++) o1[m] = k1 * x1[m];
    do_coupling<0, 1, 1>(x0, x1, half * mp[3 * 32], o1);
    do_coupling<1, 0, 1>(x1, x0, half * mp[4 * 32], o1);
    do_coupling<1, 1, 1>(x1, x1, half * mp[5 * 32], o1);
    do_coupling<1, 2, 1>(x1, x2, half * mp[6 * 32], o1);
    do_coupling<2, 1, 1>(x2, x1, half * mp[7 * 32], o1);
    do_coupling<2, 2, 1>(x2, x2, half * mp[8 * 32], o1);
#pragma unroll
    for (int m = 0; m < 3; m++)
      __builtin_nontemporal_store(o1[m], ob + 32 + m * 32);
  }

  // ---- lout = 0 ----
  {
    v4 o0[1];
    o0[0] = kp[0] * x0[0];
    do_coupling<0, 0, 0>(x0, x0, half * mp[0], o0);
    do_coupling<1, 1, 0>(x1, x1, half * mp[1 * 32], o0);
    do_coupling<2, 2, 0>(x2, x2, half * mp[2 * 32], o0);
    __builtin_nontemporal_store(o0[0], ob);
  }
}

extern "C" void kernel_launch(void* const* d_in, const int* in_sizes, int n_in,
                              void* d_out, int out_size, void* d_ws, size_t ws_size,
                              hipStream_t stream) {
  const float* x = (const float*)d_in[0];
  const float* keep = (const float*)d_in[1];
  const float* mix = (const float*)d_in[2];
  float* out = (float*)d_out;
  int B = in_sizes[0] / 1152;         // 16384
  int total = B * 32;                 // 4 channels per thread
  int blocks = (total + 255) / 256;   // 2048
  selfmix_kernel<<<blocks, 256, 0, stream>>>(x, keep, mix, out, B);
}